// Round 2
// baseline (170.353 us; speedup 1.0000x reference)
//
#include <hip/hip_runtime.h>

#define B_   2
#define L_   2048
#define H_   1024
#define NH_  16
#define KVH_ 4
#define HD_  64

typedef short short8 __attribute__((ext_vector_type(8)));
typedef float f32x4 __attribute__((ext_vector_type(4)));
typedef unsigned short u16x4 __attribute__((ext_vector_type(4)));
typedef unsigned int u32x2 __attribute__((ext_vector_type(2)));

#define LOG2E 1.4426950408889634f
#define QSC   0.18033688011112042f   /* 0.125 * log2(e) */
#define MFMA  __builtin_amdgcn_mfma_f32_16x16x32_bf16

static __device__ __forceinline__ unsigned short f2bf(float f) {
  unsigned int u = __float_as_uint(f);
  u += 0x7FFFu + ((u >> 16) & 1u);
  return (unsigned short)(u >> 16);
}

static __device__ __forceinline__ unsigned int cvtpk(float lo, float hi) {
  unsigned int r;
  asm("v_cvt_pk_bf16_f32 %0, %1, %2" : "=v"(r) : "v"(lo), "v"(hi));
  return r;
}

static __device__ __forceinline__ void gload_lds16(const void* g, void* l) {
  __builtin_amdgcn_global_load_lds(
      (const __attribute__((address_space(1))) unsigned int*)g,
      (__attribute__((address_space(3))) unsigned int*)l, 16, 0, 0);
}

// ---------------- converts ----------------
__global__ __launch_bounds__(256) void k_convert_x(const float* __restrict__ x,
                                                   unsigned short* __restrict__ xb) {
  size_t i = ((size_t)blockIdx.x * 256 + threadIdx.x) * 4;
  float4 v = *(const float4*)(x + i);
  u16x4 o = { f2bf(v.x), f2bf(v.y), f2bf(v.z), f2bf(v.w) };
  *(u16x4*)(xb + i) = o;
}

__global__ __launch_bounds__(256) void k_convert_w(const float* __restrict__ Wq,
                                                   const float* __restrict__ Wk,
                                                   const float* __restrict__ Wv,
                                                   const float* __restrict__ Wo,
                                                   unsigned short* __restrict__ wcat,
                                                   unsigned short* __restrict__ wo_b) {
  int r = blockIdx.x;
  int c = threadIdx.x * 4;
  const float* src;
  unsigned short* dst;
  if (r < 1024)      { src = Wq + (size_t)r * 1024;          dst = wcat + (size_t)r * 1024; }
  else if (r < 1280) { src = Wk + (size_t)(r - 1024) * 1024; dst = wcat + (size_t)r * 1024; }
  else if (r < 1536) { src = Wv + (size_t)(r - 1280) * 1024; dst = wcat + (size_t)r * 1024; }
  else               { src = Wo + (size_t)(r - 1536) * 1024; dst = wo_b + (size_t)(r - 1536) * 1024; }
  float4 v = *(const float4*)(src + c);
  u16x4 o = { f2bf(v.x), f2bf(v.y), f2bf(v.z), f2bf(v.w) };
  *(u16x4*)(dst + c) = o;
}

// ---------------- GEMM (m97-style 128x128x32) ----------------
template <int MODE>
__global__ __launch_bounds__(256) void k_gemm(const unsigned short* __restrict__ A,
                                              const unsigned short* __restrict__ Bt,
                                              const float* __restrict__ bias0,
                                              const float* __restrict__ bias1,
                                              const float* __restrict__ bias2,
                                              unsigned short* __restrict__ q_ws,
                                              unsigned short* __restrict__ k_ws,
                                              unsigned short* __restrict__ vt_ws,
                                              float* __restrict__ outp) {
  const int bn = blockIdx.x, bm = blockIdx.y;
  const int t = threadIdx.x;
  const int lane = t & 63, li = lane & 15, g = lane >> 4;
  const int wid = t >> 6, wr = wid >> 1, wc = wid & 1;
  __shared__ unsigned short lds_a[128 * 32];
  __shared__ unsigned short lds_b[128 * 32];

  const f32x4 z = {0.f, 0.f, 0.f, 0.f};
  f32x4 acc[4][4];
#pragma unroll
  for (int m = 0; m < 4; ++m)
#pragma unroll
    for (int n = 0; n < 4; ++n) acc[m][n] = z;

  const int c0 = t, c1 = 256 + t;
  const int r0 = c0 >> 2, o0 = (c0 & 3) * 8;
  const int r1 = c1 >> 2, o1 = (c1 & 3) * 8;
  const unsigned short* a0p = A + (size_t)(bm * 128 + r0) * 1024 + o0;
  const unsigned short* a1p = A + (size_t)(bm * 128 + r1) * 1024 + o1;
  const unsigned short* b0p = Bt + (size_t)(bn * 128 + r0) * 1024 + o0;
  const unsigned short* b1p = Bt + (size_t)(bn * 128 + r1) * 1024 + o1;

  for (int kt = 0; kt < 1024; kt += 32) {
    gload_lds16(a0p + kt, &lds_a[c0 * 8]);
    gload_lds16(a1p + kt, &lds_a[c1 * 8]);
    gload_lds16(b0p + kt, &lds_b[c0 * 8]);
    gload_lds16(b1p + kt, &lds_b[c1 * 8]);
    __syncthreads();
    short8 af[4], bf[4];
#pragma unroll
    for (int m = 0; m < 4; ++m) af[m] = *(const short8*)&lds_a[(wr * 64 + m * 16 + li) * 32 + g * 8];
#pragma unroll
    for (int n = 0; n < 4; ++n) bf[n] = *(const short8*)&lds_b[(wc * 64 + n * 16 + li) * 32 + g * 8];
#pragma unroll
    for (int m = 0; m < 4; ++m)
#pragma unroll
      for (int n = 0; n < 4; ++n)
        acc[m][n] = MFMA(af[m], bf[n], acc[m][n], 0, 0, 0);
    __syncthreads();
  }

#pragma unroll
  for (int m = 0; m < 4; ++m) {
    const int row0 = bm * 128 + wr * 64 + m * 16 + 4 * g;
#pragma unroll
    for (int n = 0; n < 4; ++n) {
      const int col = bn * 128 + wc * 64 + n * 16 + li;
      f32x4 v = acc[m][n];
      if (MODE == 1) {
        const float bias = bias0[col];
#pragma unroll
        for (int r = 0; r < 4; ++r) outp[(size_t)(row0 + r) * 1024 + col] = v[r] + bias;
      } else {
        if (col < 1024) {
          const float bias = bias0[col];
          // Q pre-scaled by 0.125*log2e so attention uses exp2 directly
#pragma unroll
          for (int r = 0; r < 4; ++r) q_ws[(size_t)(row0 + r) * 1024 + col] = f2bf((v[r] + bias) * QSC);
        } else if (col < 1280) {
          const int cc = col - 1024;
          const float bias = bias1[cc];
#pragma unroll
          for (int r = 0; r < 4; ++r) k_ws[(size_t)(row0 + r) * 256 + cc] = f2bf(v[r] + bias);
        } else {
          const int cc = col - 1280;
          const float bias = bias2[cc];
          const int kvh = cc >> 6, d = cc & 63;
          const int b = row0 >> 11, l0 = row0 & 2047;
          u16x4 pk = { f2bf(v[0] + bias), f2bf(v[1] + bias), f2bf(v[2] + bias), f2bf(v[3] + bias) };
          *(u16x4*)(vt_ws + ((size_t)((b * KVH_ + kvh) * 64 + d)) * 2048 + l0) = pk;
        }
      }
    }
  }
}

// ---------------- flash attention (GQA, 4 heads per block) ----------------
// grid (B*KVH=8, L/64=32). Wave w = query head kvh*4+w, 64 q-rows per wave.
// K/V/mask staged once per block, double-buffered, XOR-swizzled, global_load_lds.
__global__ __launch_bounds__(256, 1) void k_attn(const unsigned short* __restrict__ q_ws,
                                                 const unsigned short* __restrict__ k_ws,
                                                 const unsigned short* __restrict__ vt_ws,
                                                 const float* __restrict__ mask,
                                                 unsigned short* __restrict__ ctx) {
  const int bk = blockIdx.x;        // b*4 + kvh
  const int qt = blockIdx.y;
  const int b = bk >> 2, kvh = bk & 3;
  const int t = threadIdx.x;
  const int wid = t >> 6, lane = t & 63, li = lane & 15, g = lane >> 4;
  const int h = kvh * 4 + wid;

  __shared__ unsigned short lds_k[2][64 * 64];   // [kj][d], granule^=(kj&7)
  __shared__ unsigned short lds_v[2][64 * 64];   // [d][kj], granule^=(d&7)
  __shared__ float lds_m[2][64 * 64];            // [qi][kj] f32, granule^=(qi&7)
  __shared__ unsigned short lds_p[4][16 * 72];   // per-wave P [qi][kj], +8 pad

  // ---- Q preload (pre-scaled in GEMM epilogue) ----
  short8 qf[4][2];
#pragma unroll
  for (int qif = 0; qif < 4; ++qif)
#pragma unroll
    for (int hh = 0; hh < 2; ++hh)
      qf[qif][hh] = *(const short8*)(q_ws +
          ((size_t)b * L_ + qt * 64 + qif * 16 + li) * H_ + h * HD_ + hh * 32 + g * 8);

  const f32x4 z = {0.f, 0.f, 0.f, 0.f};
  f32x4 o[4][4];
#pragma unroll
  for (int qif = 0; qif < 4; ++qif)
#pragma unroll
    for (int db = 0; db < 4; ++db) o[qif][db] = z;
  float m_run[4] = {-INFINITY, -INFINITY, -INFINITY, -INFINITY};
  float l_run[4] = {0.f, 0.f, 0.f, 0.f};

  // ---- staging base pointers (pre-swizzled global sources) ----
  const int l3 = lane >> 3, l7 = lane & 7;        // K/V: row-in-chunk, granule
  const int swkv = (l7 ^ l3) * 8;                 // swizzled d-granule (shorts)
  const unsigned short* kbase = k_ws + ((size_t)b * L_ + wid * 16 + l3) * 256 + kvh * 64 + swkv;
  const unsigned short* vbase = vt_ws + ((size_t)(b * KVH_ + kvh) * 64 + wid * 16 + l3) * 2048 + swkv;
  const int l4 = lane >> 4, l15 = lane & 15;      // mask: row-in-chunk, granule
  const float* mbaseA = mask + ((size_t)b * L_ + qt * 64 + wid * 16 + l4) * 2048 + ((l15 ^ l4) * 4);
  const float* mbaseB = mask + ((size_t)b * L_ + qt * 64 + wid * 16 + l4) * 2048 + ((l15 ^ (4 + l4)) * 4);

  auto stage = [&](int buf, int kt) {
#pragma unroll
    for (int i = 0; i < 2; ++i) {
      gload_lds16(kbase + (size_t)kt * 16384 + i * 2048, &lds_k[buf][(wid * 2 + i) * 512 + lane * 8]);
      gload_lds16(vbase + kt * 64 + i * 16384, &lds_v[buf][(wid * 2 + i) * 512 + lane * 8]);
    }
#pragma unroll
    for (int i = 0; i < 4; ++i) {
      const float* ms = ((i & 1) ? mbaseB : mbaseA) + (size_t)(i * 4) * 2048 + kt * 64;
      gload_lds16(ms, &lds_m[buf][(wid * 4 + i) * 256 + lane * 4]);
    }
  };

  const int sw0 = (g ^ (li & 7)) * 8;             // frag-read swizzled granules
  const int sw1 = ((4 + g) ^ (li & 7)) * 8;
  unsigned short* pw = &lds_p[wid][0];

  auto compute = [&](int buf) {
    short8 kf[4][2], vf[4][2];
#pragma unroll
    for (int x = 0; x < 4; ++x) {
      const int rb = (x * 16 + li) * 64;
      kf[x][0] = *(const short8*)&lds_k[buf][rb + sw0];
      kf[x][1] = *(const short8*)&lds_k[buf][rb + sw1];
      vf[x][0] = *(const short8*)&lds_v[buf][rb + sw0];
      vf[x][1] = *(const short8*)&lds_v[buf][rb + sw1];
    }
#pragma unroll
    for (int qif = 0; qif < 4; ++qif) {
      f32x4 sv[4];
#pragma unroll
      for (int kb = 0; kb < 4; ++kb) {
        sv[kb] = MFMA(kf[kb][0], qf[qif][0], z, 0, 0, 0);
        sv[kb] = MFMA(kf[kb][1], qf[qif][1], sv[kb], 0, 0, 0);
      }
#pragma unroll
      for (int kb = 0; kb < 4; ++kb) {
        f32x4 mv = *(const f32x4*)&lds_m[buf][(qif * 16 + li) * 64 + (((kb * 4 + g) ^ (li & 7)) * 4)];
#pragma unroll
        for (int r = 0; r < 4; ++r) sv[kb][r] = fmaf(mv[r], LOG2E, sv[kb][r]);
      }
      // row max (log2 domain)
      float tm = fmaxf(fmaxf(sv[0][0], sv[0][1]), fmaxf(sv[0][2], sv[0][3]));
#pragma unroll
      for (int kb = 1; kb < 4; ++kb)
        tm = fmaxf(tm, fmaxf(fmaxf(sv[kb][0], sv[kb][1]), fmaxf(sv[kb][2], sv[kb][3])));
      tm = fmaxf(tm, __shfl_xor(tm, 16));
      tm = fmaxf(tm, __shfl_xor(tm, 32));
      float mq = m_run[qif];
      if (!__all(tm <= mq + 11.0f)) {           // defer-max (T13)
        const float mnew = fmaxf(mq, tm);
        const float corr = exp2f(mq - mnew);
        l_run[qif] *= corr;
#pragma unroll
        for (int db = 0; db < 4; ++db) {
          o[qif][db][0] *= corr; o[qif][db][1] *= corr;
          o[qif][db][2] *= corr; o[qif][db][3] *= corr;
        }
        m_run[qif] = mnew; mq = mnew;
      }
      float ts = 0.f;
#pragma unroll
      for (int kb = 0; kb < 4; ++kb)
#pragma unroll
        for (int r = 0; r < 4; ++r) {
          const float p = exp2f(sv[kb][r] - mq);
          sv[kb][r] = p;
          ts += p;
        }
      ts += __shfl_xor(ts, 16);
      ts += __shfl_xor(ts, 32);
      l_run[qif] += ts;
      // P -> bf16 -> per-wave LDS [qi][kj]
#pragma unroll
      for (int kb = 0; kb < 4; ++kb) {
        u32x2 pk = { cvtpk(sv[kb][0], sv[kb][1]), cvtpk(sv[kb][2], sv[kb][3]) };
        *(u32x2*)&pw[li * 72 + kb * 16 + 4 * g] = pk;
      }
#pragma unroll
      for (int kjh = 0; kjh < 2; ++kjh) {
        short8 pb = *(const short8*)&pw[li * 72 + kjh * 32 + g * 8];
#pragma unroll
        for (int db = 0; db < 4; ++db)
          o[qif][db] = MFMA(vf[db][kjh], pb, o[qif][db], 0, 0, 0);
      }
    }
  };

  stage(0, 0);
  __syncthreads();
#pragma unroll 1
  for (int kt = 0; kt < 32; kt += 2) {
    if (kt + 1 < 32) stage(1, kt + 1);
    compute(0);
    __syncthreads();
    if (kt + 2 < 32) stage(0, kt + 2);
    compute(1);
    __syncthreads();
  }

  // ---- epilogue ----
#pragma unroll
  for (int qif = 0; qif < 4; ++qif) {
    const float inv = 1.0f / l_run[qif];
    unsigned short* cp = ctx + ((size_t)b * L_ + qt * 64 + qif * 16 + li) * H_ + h * HD_;
#pragma unroll
    for (int db = 0; db < 4; ++db) {
      u32x2 pk = { cvtpk(o[qif][db][0] * inv, o[qif][db][1] * inv),
                   cvtpk(o[qif][db][2] * inv, o[qif][db][3] * inv) };
      *(u32x2*)(cp + db * 16 + 4 * g) = pk;
    }
  }
}

// ---------------- launch ----------------
extern "C" void kernel_launch(void* const* d_in, const int* in_sizes, int n_in,
                              void* d_out, int out_size, void* d_ws, size_t ws_size,
                              hipStream_t stream) {
  const float* x    = (const float*)d_in[0];
  const float* mask = (const float*)d_in[1];
  const float* Wq   = (const float*)d_in[2];
  const float* bq   = (const float*)d_in[3];
  const float* Wk   = (const float*)d_in[4];
  const float* bk   = (const float*)d_in[5];
  const float* Wv   = (const float*)d_in[6];
  const float* bv   = (const float*)d_in[7];
  const float* Wo   = (const float*)d_in[8];
  const float* bo   = (const float*)d_in[9];
  float* out = (float*)d_out;

  char* ws = (char*)d_ws;
  unsigned short* xb    = (unsigned short*)(ws);                 // 8 MB (reused as ctx)
  unsigned short* ctx   = xb;
  unsigned short* wcat  = (unsigned short*)(ws + 8388608);       // 3 MB
  unsigned short* wo_b  = (unsigned short*)(ws + 11534336);      // 2 MB
  unsigned short* q_ws  = (unsigned short*)(ws + 13631488);      // 8 MB
  unsigned short* k_ws  = (unsigned short*)(ws + 22020096);      // 2 MB
  unsigned short* vt_ws = (unsigned short*)(ws + 24117248);      // 2 MB

  k_convert_x<<<dim3(4096), dim3(256), 0, stream>>>(x, xb);
  k_convert_w<<<dim3(2560), dim3(256), 0, stream>>>(Wq, Wk, Wv, Wo, wcat, wo_b);
  k_gemm<0><<<dim3(12, 32), dim3(256), 0, stream>>>(xb, wcat, bq, bk, bv, q_ws, k_ws, vt_ws, nullptr);
  k_attn<<<dim3(8, 32), dim3(256), 0, stream>>>(q_ws, k_ws, vt_ws, mask, ctx);
  k_gemm<1><<<dim3(8, 32), dim3(256), 0, stream>>>(ctx, wo_b, bo, nullptr, nullptr,
                                                   nullptr, nullptr, nullptr, out);
}